// Round 1
// baseline (158.189 us; speedup 1.0000x reference)
//
#include <hip/hip_runtime.h>
#include <hip/hip_bf16.h>

#define NROWS 8192
#define DCOLS 256
constexpr float EPSV = 1e-6f;

typedef __attribute__((ext_vector_type(8))) short short8;
typedef __attribute__((ext_vector_type(4))) float f32x4;

// ---------------- K1: row norms (+ zero accumulators) ----------------
__global__ void k1_norms(const float* __restrict__ in, float* __restrict__ inv,
                         float* __restrict__ colsum, double* __restrict__ sumdist) {
    int row = blockIdx.x;
    int t = threadIdx.x;
    int lane = t & 63, wave = t >> 6;
    float x = in[row * DCOLS + t];
    float s = x * x;
    #pragma unroll
    for (int o = 1; o < 64; o <<= 1) s += __shfl_xor(s, o);
    __shared__ float red[4];
    if (lane == 0) red[wave] = s;
    __syncthreads();
    if (t == 0) {
        float tot = red[0] + red[1] + red[2] + red[3];
        inv[row] = 1.0f / (sqrtf(tot) + EPSV);
    }
    if (blockIdx.x == 0) {
        if (t < DCOLS) colsum[t] = 0.0f;
        if (t == 0) *sumdist = 0.0;
    }
}

// ---------------- K2: column sums of normalized e ----------------
__global__ void k2_colsum(const float* __restrict__ in, const float* __restrict__ inv,
                          float* __restrict__ colsum) {
    int t = threadIdx.x;
    int r0 = blockIdx.x * 32;
    float local = 0.0f;
    #pragma unroll 4
    for (int rr = 0; rr < 32; ++rr) {
        int r = r0 + rr;
        local += in[r * DCOLS + t] * inv[r];
    }
    atomicAdd(&colsum[t], local);
}

// ---------------- K3: center, write bf16 c, per-row sq_norms ----------------
__global__ void k3_center(const float* __restrict__ in, const float* __restrict__ inv,
                          const float* __restrict__ colsum,
                          __hip_bfloat16* __restrict__ cbf, float* __restrict__ sqn) {
    int t = threadIdx.x;
    int lane = t & 63, wave = t >> 6;
    int r0 = blockIdx.x * 32;
    float mean = colsum[t] * (1.0f / NROWS);
    __shared__ float part[32][4];
    for (int rr = 0; rr < 32; ++rr) {
        int r = r0 + rr;
        float cv = in[r * DCOLS + t] * inv[r] - mean;
        cbf[r * DCOLS + t] = __float2bfloat16(cv);
        float s = cv * cv;
        #pragma unroll
        for (int o = 1; o < 64; o <<= 1) s += __shfl_xor(s, o);
        if (lane == 0) part[rr][wave] = s;
    }
    __syncthreads();
    if (t < 32) sqn[r0 + t] = part[t][0] + part[t][1] + part[t][2] + part[t][3];
}

// ---------------- K4: tiled bf16 MFMA gram + distance accumulate ----------------
// 128x128 tile per block, 4 waves (2x2), each wave 64x64 = 4x4 fragments of 16x16.
// Upper-triangle tile grid (p<=q), off-diagonal tiles weighted 2x by symmetry.
__global__ __launch_bounds__(256) void k4_dist(const __hip_bfloat16* __restrict__ cbf,
                                               const float* __restrict__ sqn,
                                               double* __restrict__ sumdist) {
    __shared__ ushort As[128 * 64];
    __shared__ ushort Bs[128 * 64];

    int idx = blockIdx.x;
    // decode upper-triangular tile index: idx = q*(q+1)/2 + p, p<=q
    int q = (int)((sqrt(8.0 * (double)idx + 1.0) - 1.0) * 0.5);
    while ((q + 1) * (q + 2) / 2 <= idx) ++q;
    while (q * (q + 1) / 2 > idx) --q;
    int p = idx - q * (q + 1) / 2;

    int brow = p * 128, bcol = q * 128;
    int t = threadIdx.x, lane = t & 63, wave = t >> 6;
    int wr = wave >> 1, wc = wave & 1;

    f32x4 acc[4][4] = {};

    for (int k0 = 0; k0 < DCOLS; k0 += 64) {
        // stage A (rows of tile p) and B (rows of tile q), 128x64 bf16 each, XOR-swizzled
        #pragma unroll
        for (int ppass = 0; ppass < 4; ++ppass) {
            int id = ppass * 256 + t;          // 0..1023
            int row = id >> 3, ch = id & 7;
            int off = ((row * 128 + ch * 16) ^ ((row & 7) << 4));
            uint4 va = *reinterpret_cast<const uint4*>(&cbf[(brow + row) * DCOLS + k0 + ch * 8]);
            *reinterpret_cast<uint4*>(reinterpret_cast<char*>(As) + off) = va;
            uint4 vb = *reinterpret_cast<const uint4*>(&cbf[(bcol + row) * DCOLS + k0 + ch * 8]);
            *reinterpret_cast<uint4*>(reinterpret_cast<char*>(Bs) + off) = vb;
        }
        __syncthreads();
        #pragma unroll
        for (int kk = 0; kk < 2; ++kk) {
            short8 af[4], bfr[4];
            int bc = kk * 64 + (lane >> 4) * 16;
            #pragma unroll
            for (int m = 0; m < 4; ++m) {
                int row = wr * 64 + m * 16 + (lane & 15);
                int off = (row * 128 + bc) ^ ((row & 7) << 4);
                af[m] = *reinterpret_cast<const short8*>(reinterpret_cast<char*>(As) + off);
            }
            #pragma unroll
            for (int n = 0; n < 4; ++n) {
                int row = wc * 64 + n * 16 + (lane & 15);
                int off = (row * 128 + bc) ^ ((row & 7) << 4);
                bfr[n] = *reinterpret_cast<const short8*>(reinterpret_cast<char*>(Bs) + off);
            }
            #pragma unroll
            for (int m = 0; m < 4; ++m)
                #pragma unroll
                for (int n = 0; n < 4; ++n)
                    acc[m][n] = __builtin_amdgcn_mfma_f32_16x16x32_bf16(af[m], bfr[n], acc[m][n], 0, 0, 0);
        }
        __syncthreads();
    }

    // epilogue: sq_dist = sqn_i + sqn_j - 2*gram; accumulate sqrt
    float local = 0.0f;
    int r4 = (lane >> 4) * 4;
    int cn = lane & 15;
    #pragma unroll
    for (int n = 0; n < 4; ++n) {
        int j = bcol + wc * 64 + n * 16 + cn;
        float sj = sqn[j];
        #pragma unroll
        for (int m = 0; m < 4; ++m) {
            int i0 = brow + wr * 64 + m * 16 + r4;
            #pragma unroll
            for (int r = 0; r < 4; ++r) {
                float sq = sqn[i0 + r] + sj - 2.0f * acc[m][n][r];
                local += (sq > 0.0f) ? sqrtf(sq) : 0.0f;
            }
        }
    }
    #pragma unroll
    for (int o = 1; o < 64; o <<= 1) local += __shfl_xor(local, o);
    if (lane == 0) {
        float w = (p == q) ? 1.0f : 2.0f;
        atomicAdd(sumdist, (double)(w * local));
    }
}

// ---------------- K5: final scalar ----------------
__global__ void k5_final(const float* __restrict__ sqn, const double* __restrict__ sumdist,
                         float* __restrict__ out) {
    int t = threadIdx.x;
    int lane = t & 63, wave = t >> 6;
    float s = 0.0f;
    for (int r = t; r < NROWS; r += 256) s += sqn[r];
    #pragma unroll
    for (int o = 1; o < 64; o <<= 1) s += __shfl_xor(s, o);
    __shared__ float red[4];
    if (lane == 0) red[wave] = s;
    __syncthreads();
    if (t == 0) {
        float sumsq = red[0] + red[1] + red[2] + red[3];
        double md = *sumdist / ((double)NROWS * (double)NROWS);
        float var = sumsq / (float)DCOLS;
        out[0] = 1.0f / var + (float)log(md);
    }
}

extern "C" void kernel_launch(void* const* d_in, const int* in_sizes, int n_in,
                              void* d_out, int out_size, void* d_ws, size_t ws_size,
                              hipStream_t stream) {
    const float* emb = (const float*)d_in[0];
    float* out = (float*)d_out;
    char* ws = (char*)d_ws;

    float*  inv     = (float*)ws;                    // 8192 f32  -> 32768 B
    float*  colsum  = (float*)(ws + 32768);          // 256 f32   -> 1024 B
    double* sumdist = (double*)(ws + 33792);         // 8 B
    float*  sqn     = (float*)(ws + 36864);          // 8192 f32
    __hip_bfloat16* cbf = (__hip_bfloat16*)(ws + 131072); // 8192*256 bf16 = 4 MB

    k1_norms  <<<NROWS, 256, 0, stream>>>(emb, inv, colsum, sumdist);
    k2_colsum <<<NROWS / 32, 256, 0, stream>>>(emb, inv, colsum);
    k3_center <<<NROWS / 32, 256, 0, stream>>>(emb, inv, colsum, cbf, sqn);
    k4_dist   <<<(64 * 65) / 2, 256, 0, stream>>>(cbf, sqn, sumdist);
    k5_final  <<<1, 256, 0, stream>>>(sqn, sumdist, out);
}

// Round 3
// 89.724 us; speedup vs baseline: 1.7631x; 1.7631x over previous
//
#include <hip/hip_runtime.h>
#include <hip/hip_bf16.h>

#define NROWS 8192
#define DCOLS 256
#define NTILES 2080   // 64*65/2 upper-triangle 128x128 tiles
constexpr float EPSV = 1e-6f;

typedef __attribute__((ext_vector_type(8))) short short8;
typedef __attribute__((ext_vector_type(4))) float f32x4;

// ---------------- K12: fused row norms + column sums ----------------
// 256 blocks x 256 threads; each block owns 32 rows (8 per wave).
__global__ void k12_fused(const float* __restrict__ in, float* __restrict__ inv,
                          float* __restrict__ colsum) {
    int t = threadIdx.x, lane = t & 63, wave = t >> 6;
    int r0 = blockIdx.x * 32;
    __shared__ float invs[32];
    // phase 1: wave w handles rows r0 + w*8 .. +7; lane covers 4 cols each
    #pragma unroll
    for (int rr = 0; rr < 8; ++rr) {
        int row = r0 + wave * 8 + rr;
        const float4 v = *reinterpret_cast<const float4*>(&in[row * DCOLS + lane * 4]);
        float s = v.x * v.x + v.y * v.y + v.z * v.z + v.w * v.w;
        #pragma unroll
        for (int o = 1; o < 64; o <<= 1) s += __shfl_xor(s, o);
        if (lane == 0) {
            float iv = 1.0f / (sqrtf(s) + EPSV);
            invs[wave * 8 + rr] = iv;
            inv[row] = iv;
        }
    }
    __syncthreads();
    // phase 2: thread t = column t across the 32 rows (L1/L2 warm)
    float local = 0.0f;
    #pragma unroll 4
    for (int rr = 0; rr < 32; ++rr)
        local += in[(r0 + rr) * DCOLS + t] * invs[rr];
    atomicAdd(&colsum[t], local);
}

// ---------------- K3: center, write bf16 c, per-row sq_norms ----------------
__global__ void k3_center(const float* __restrict__ in, const float* __restrict__ inv,
                          const float* __restrict__ colsum,
                          __hip_bfloat16* __restrict__ cbf, float* __restrict__ sqn) {
    int t = threadIdx.x;
    int lane = t & 63, wave = t >> 6;
    int r0 = blockIdx.x * 32;
    float mean = colsum[t] * (1.0f / NROWS);
    __shared__ float part[32][4];
    for (int rr = 0; rr < 32; ++rr) {
        int r = r0 + rr;
        float cv = in[r * DCOLS + t] * inv[r] - mean;
        cbf[r * DCOLS + t] = __float2bfloat16(cv);
        float s = cv * cv;
        #pragma unroll
        for (int o = 1; o < 64; o <<= 1) s += __shfl_xor(s, o);
        if (lane == 0) part[rr][wave] = s;
    }
    __syncthreads();
    if (t < 32) sqn[r0 + t] = part[t][0] + part[t][1] + part[t][2] + part[t][3];
}

// ---------------- K4: tiled bf16 MFMA gram + distance accumulate ----------------
// 128x128 tile per block, 4 waves (2x2), each wave 64x64 = 4x4 fragments of 16x16.
// Upper-triangle tile grid (p<=q), off-diagonal tiles weighted 2x by symmetry.
// NO atomics: per-block partial -> partial[blockIdx.x].
__global__ __launch_bounds__(256) void k4_dist(const __hip_bfloat16* __restrict__ cbf,
                                               const float* __restrict__ sqn,
                                               float* __restrict__ partial) {
    __shared__ ushort As[128 * 64];
    __shared__ ushort Bs[128 * 64];
    __shared__ float red4[4];

    int idx = blockIdx.x;
    // decode upper-triangular tile index: idx = q*(q+1)/2 + p, p<=q
    int q = (int)((sqrt(8.0 * (double)idx + 1.0) - 1.0) * 0.5);
    while ((q + 1) * (q + 2) / 2 <= idx) ++q;
    while (q * (q + 1) / 2 > idx) --q;
    int p = idx - q * (q + 1) / 2;

    int brow = p * 128, bcol = q * 128;
    int t = threadIdx.x, lane = t & 63, wave = t >> 6;
    int wr = wave >> 1, wc = wave & 1;

    f32x4 acc[4][4] = {};

    for (int k0 = 0; k0 < DCOLS; k0 += 64) {
        // stage A (rows of tile p) and B (rows of tile q), 128x64 bf16 each, XOR-swizzled
        #pragma unroll
        for (int ppass = 0; ppass < 4; ++ppass) {
            int id = ppass * 256 + t;          // 0..1023
            int row = id >> 3, ch = id & 7;
            int off = ((row * 128 + ch * 16) ^ ((row & 7) << 4));
            uint4 va = *reinterpret_cast<const uint4*>(&cbf[(brow + row) * DCOLS + k0 + ch * 8]);
            *reinterpret_cast<uint4*>(reinterpret_cast<char*>(As) + off) = va;
            uint4 vb = *reinterpret_cast<const uint4*>(&cbf[(bcol + row) * DCOLS + k0 + ch * 8]);
            *reinterpret_cast<uint4*>(reinterpret_cast<char*>(Bs) + off) = vb;
        }
        __syncthreads();
        #pragma unroll
        for (int kk = 0; kk < 2; ++kk) {
            short8 af[4], bfr[4];
            int bc = kk * 64 + (lane >> 4) * 16;
            #pragma unroll
            for (int m = 0; m < 4; ++m) {
                int row = wr * 64 + m * 16 + (lane & 15);
                int off = (row * 128 + bc) ^ ((row & 7) << 4);
                af[m] = *reinterpret_cast<const short8*>(reinterpret_cast<char*>(As) + off);
            }
            #pragma unroll
            for (int n = 0; n < 4; ++n) {
                int row = wc * 64 + n * 16 + (lane & 15);
                int off = (row * 128 + bc) ^ ((row & 7) << 4);
                bfr[n] = *reinterpret_cast<const short8*>(reinterpret_cast<char*>(Bs) + off);
            }
            #pragma unroll
            for (int m = 0; m < 4; ++m)
                #pragma unroll
                for (int n = 0; n < 4; ++n)
                    acc[m][n] = __builtin_amdgcn_mfma_f32_16x16x32_bf16(af[m], bfr[n], acc[m][n], 0, 0, 0);
        }
        __syncthreads();
    }

    // epilogue: sq_dist = sqn_i + sqn_j - 2*gram; accumulate sqrt
    float local = 0.0f;
    int r4 = (lane >> 4) * 4;
    int cn = lane & 15;
    #pragma unroll
    for (int n = 0; n < 4; ++n) {
        int j = bcol + wc * 64 + n * 16 + cn;
        float sj = sqn[j];
        #pragma unroll
        for (int m = 0; m < 4; ++m) {
            int i0 = brow + wr * 64 + m * 16 + r4;
            #pragma unroll
            for (int r = 0; r < 4; ++r) {
                float sq = sqn[i0 + r] + sj - 2.0f * acc[m][n][r];
                local += (sq > 0.0f) ? sqrtf(sq) : 0.0f;
            }
        }
    }
    #pragma unroll
    for (int o = 1; o < 64; o <<= 1) local += __shfl_xor(local, o);
    if (lane == 0) red4[wave] = local;
    __syncthreads();
    if (t == 0) {
        float w = (p == q) ? 1.0f : 2.0f;
        partial[idx] = w * (red4[0] + red4[1] + red4[2] + red4[3]);
    }
}

// ---------------- K5: final scalar ----------------
__global__ void k5_final(const float* __restrict__ sqn, const float* __restrict__ partial,
                         float* __restrict__ out) {
    int t = threadIdx.x;
    int lane = t & 63, wave = t >> 6;
    float s = 0.0f;
    for (int r = t; r < NROWS; r += 256) s += sqn[r];
    double ds = 0.0;
    for (int r = t; r < NTILES; r += 256) ds += (double)partial[r];
    #pragma unroll
    for (int o = 1; o < 64; o <<= 1) { s += __shfl_xor(s, o); ds += __shfl_xor(ds, o); }
    __shared__ float redf[4];
    __shared__ double redd[4];
    if (lane == 0) { redf[wave] = s; redd[wave] = ds; }
    __syncthreads();
    if (t == 0) {
        float sumsq = redf[0] + redf[1] + redf[2] + redf[3];
        double md = (redd[0] + redd[1] + redd[2] + redd[3]) / ((double)NROWS * (double)NROWS);
        out[0] = (float)DCOLS / sumsq + (float)log(md);
    }
}

extern "C" void kernel_launch(void* const* d_in, const int* in_sizes, int n_in,
                              void* d_out, int out_size, void* d_ws, size_t ws_size,
                              hipStream_t stream) {
    const float* emb = (const float*)d_in[0];
    float* out = (float*)d_out;
    char* ws = (char*)d_ws;

    float*  inv     = (float*)ws;                    // 8192 f32
    float*  colsum  = (float*)(ws + 32768);          // 256 f32
    float*  sqn     = (float*)(ws + 36864);          // 8192 f32
    float*  partial = (float*)(ws + 69632);          // 2080 f32
    __hip_bfloat16* cbf = (__hip_bfloat16*)(ws + 131072); // 8192*256 bf16 = 4 MB

    hipMemsetAsync(colsum, 0, DCOLS * sizeof(float), stream);
    k12_fused <<<NROWS / 32, 256, 0, stream>>>(emb, inv, colsum);
    k3_center <<<NROWS / 32, 256, 0, stream>>>(emb, inv, colsum, cbf, sqn);
    k4_dist   <<<NTILES, 256, 0, stream>>>(cbf, sqn, partial);
    k5_final  <<<1, 256, 0, stream>>>(sqn, partial, out);
}

// Round 4
// 76.021 us; speedup vs baseline: 2.0809x; 1.1803x over previous
//
#include <hip/hip_runtime.h>
#include <hip/hip_bf16.h>

#define NROWS 8192
#define DCOLS 256
#define NTILES 2080   // 64*65/2 upper-triangle 128x128 tiles
constexpr float EPSV = 1e-6f;

typedef __attribute__((ext_vector_type(8))) short short8;
typedef __attribute__((ext_vector_type(4))) float f32x4;

__device__ __forceinline__ void async16(void* lds, const void* g) {
    __builtin_amdgcn_global_load_lds(
        (const __attribute__((address_space(1))) void*)g,
        (__attribute__((address_space(3))) void*)lds, 16, 0, 0);
}

// ---------------- K12: row norms + column sums, single pass ----------------
// 256 blocks x 256 threads; block owns 32 rows (8 per wave); lane covers 4 cols.
__global__ void k12_fused(const float* __restrict__ in, float* __restrict__ inv,
                          float* __restrict__ colsum) {
    int t = threadIdx.x, lane = t & 63, wave = t >> 6;
    int r0 = blockIdx.x * 32;
    __shared__ float cs[4][256];
    float4 acc4 = {0.f, 0.f, 0.f, 0.f};
    #pragma unroll
    for (int rr = 0; rr < 8; ++rr) {
        int row = r0 + wave * 8 + rr;
        float4 v = *reinterpret_cast<const float4*>(&in[row * DCOLS + lane * 4]);
        float s = v.x * v.x + v.y * v.y + v.z * v.z + v.w * v.w;
        #pragma unroll
        for (int o = 1; o < 64; o <<= 1) s += __shfl_xor(s, o);
        float iv = 1.0f / (sqrtf(s) + EPSV);   // all lanes have s after butterfly
        if (lane == 0) inv[row] = iv;
        acc4.x += v.x * iv; acc4.y += v.y * iv; acc4.z += v.z * iv; acc4.w += v.w * iv;
    }
    *reinterpret_cast<float4*>(&cs[wave][lane * 4]) = acc4;
    __syncthreads();
    atomicAdd(&colsum[t], cs[0][t] + cs[1][t] + cs[2][t] + cs[3][t]);
}

// ---------------- K3: center, write bf16 c, per-row sq_norms ----------------
__global__ void k3_center(const float* __restrict__ in, const float* __restrict__ inv,
                          const float* __restrict__ colsum,
                          __hip_bfloat16* __restrict__ cbf, float* __restrict__ sqn) {
    int t = threadIdx.x, lane = t & 63, wave = t >> 6;
    int r0 = blockIdx.x * 32;
    float4 m4 = *reinterpret_cast<const float4*>(&colsum[lane * 4]);
    const float invN = 1.0f / NROWS;
    m4.x *= invN; m4.y *= invN; m4.z *= invN; m4.w *= invN;
    #pragma unroll
    for (int rr = 0; rr < 8; ++rr) {
        int row = r0 + wave * 8 + rr;
        float iv = inv[row];
        float4 v = *reinterpret_cast<const float4*>(&in[row * DCOLS + lane * 4]);
        float4 cv = {v.x * iv - m4.x, v.y * iv - m4.y, v.z * iv - m4.z, v.w * iv - m4.w};
        __hip_bfloat16 hb[4] = {__float2bfloat16(cv.x), __float2bfloat16(cv.y),
                                __float2bfloat16(cv.z), __float2bfloat16(cv.w)};
        *reinterpret_cast<ushort4*>(&cbf[row * DCOLS + lane * 4]) = *reinterpret_cast<ushort4*>(hb);
        float s = cv.x * cv.x + cv.y * cv.y + cv.z * cv.z + cv.w * cv.w;
        #pragma unroll
        for (int o = 1; o < 64; o <<= 1) s += __shfl_xor(s, o);
        if (lane == 0) sqn[row] = s;
    }
}

// ---------------- K4: tiled bf16 MFMA gram + distance accumulate ----------------
// 128x128 tile per block, 4 waves (2x2), each wave 64x64 = 4x4 fragments of 16x16.
// Upper-triangle grid (p<=q), off-diagonal weighted 2x. global_load_lds staging,
// double-buffered BK=64, swizzle applied on the GLOBAL source (LDS dest linear).
__global__ __launch_bounds__(256, 2) void k4_dist(const __hip_bfloat16* __restrict__ cbf,
                                                  const float* __restrict__ sqn,
                                                  float* __restrict__ partial) {
    __shared__ ushort As[2][128 * 64];   // 2 x 16KB
    __shared__ ushort Bs[2][128 * 64];
    __shared__ float red4[4];

    // XCD-aware swizzle (2080 % 8 == 0): each XCD gets a contiguous idx chunk
    int bid = blockIdx.x;
    int idx = (bid & 7) * (NTILES / 8) + (bid >> 3);
    // decode upper-triangular tile index: idx = q*(q+1)/2 + p, p<=q
    int q = (int)((sqrtf(8.0f * (float)idx + 1.0f) - 1.0f) * 0.5f);
    while ((q + 1) * (q + 2) / 2 <= idx) ++q;
    while (q * (q + 1) / 2 > idx) --q;
    int p = idx - q * (q + 1) / 2;

    int brow = p * 128, bcol = q * 128;
    int t = threadIdx.x, lane = t & 63, wave = t >> 6;
    int wr = wave >> 1, wc = wave & 1;

    // Staging: per call, 64 lanes write 1KB linear = 8 LDS rows of 128B.
    // lane l -> LDS row r0+(l>>3), chunk (l&7). Source chunk pre-XORed by (row&7)
    // so that LDS[X] = G[X ^ ((row&7)<<4)], matching the reader's XOR.
    int laneOff = ((lane >> 3) * 512) + ((((lane & 7) ^ (lane >> 3)) & 7) << 4);
    const char* Ab = (const char*)cbf + (size_t)brow * 512 + laneOff;
    const char* Bb = (const char*)cbf + (size_t)bcol * 512 + laneOff;

    f32x4 acc[4][4] = {};

    // prologue stage of buffer 0 (k-slice 0)
    #pragma unroll
    for (int c = 0; c < 4; ++c) {
        int r0 = wave * 32 + c * 8;
        async16(&As[0][r0 * 64], Ab + r0 * 512);
        async16(&Bs[0][r0 * 64], Bb + r0 * 512);
    }
    __syncthreads();

    #pragma unroll
    for (int s = 0; s < 4; ++s) {
        if (s < 3) {   // issue next k-slice into the other buffer; lands by barrier
            int nb = (s + 1) & 1, kb = (s + 1) * 128;
            #pragma unroll
            for (int c = 0; c < 4; ++c) {
                int r0 = wave * 32 + c * 8;
                async16(&As[nb][r0 * 64], Ab + r0 * 512 + kb);
                async16(&Bs[nb][r0 * 64], Bb + r0 * 512 + kb);
            }
        }
        int b = s & 1;
        #pragma unroll
        for (int kk = 0; kk < 2; ++kk) {
            short8 af[4], bfr[4];
            int bc = kk * 64 + ((lane >> 4) << 4);
            #pragma unroll
            for (int m = 0; m < 4; ++m) {
                int row = wr * 64 + m * 16 + (lane & 15);
                int off = (row * 128 + bc) ^ ((row & 7) << 4);
                af[m] = *reinterpret_cast<const short8*>(reinterpret_cast<const char*>(As[b]) + off);
            }
            #pragma unroll
            for (int n = 0; n < 4; ++n) {
                int row = wc * 64 + n * 16 + (lane & 15);
                int off = (row * 128 + bc) ^ ((row & 7) << 4);
                bfr[n] = *reinterpret_cast<const short8*>(reinterpret_cast<const char*>(Bs[b]) + off);
            }
            #pragma unroll
            for (int m = 0; m < 4; ++m)
                #pragma unroll
                for (int n = 0; n < 4; ++n)
                    acc[m][n] = __builtin_amdgcn_mfma_f32_16x16x32_bf16(af[m], bfr[n], acc[m][n], 0, 0, 0);
        }
        __syncthreads();   // drains vmcnt(0): next buffer staged, current free
    }

    // epilogue: sq_dist = sqn_i + sqn_j - 2*gram; accumulate sqrt
    float local = 0.0f;
    int r4 = (lane >> 4) * 4;
    int cn = lane & 15;
    #pragma unroll
    for (int n = 0; n < 4; ++n) {
        int j = bcol + wc * 64 + n * 16 + cn;
        float sj = sqn[j];
        #pragma unroll
        for (int m = 0; m < 4; ++m) {
            int i0 = brow + wr * 64 + m * 16 + r4;
            #pragma unroll
            for (int r = 0; r < 4; ++r) {
                float sq = sqn[i0 + r] + sj - 2.0f * acc[m][n][r];
                local += (sq > 0.0f) ? sqrtf(sq) : 0.0f;
            }
        }
    }
    #pragma unroll
    for (int o = 1; o < 64; o <<= 1) local += __shfl_xor(local, o);
    if (lane == 0) red4[wave] = local;
    __syncthreads();
    if (t == 0) {
        float w = (p == q) ? 1.0f : 2.0f;
        partial[idx] = w * (red4[0] + red4[1] + red4[2] + red4[3]);
    }
}

// ---------------- K5: final scalar ----------------
__global__ void k5_final(const float* __restrict__ sqn, const float* __restrict__ partial,
                         float* __restrict__ out) {
    int t = threadIdx.x;
    int lane = t & 63, wave = t >> 6;
    float s = 0.0f;
    for (int r = t; r < NROWS; r += 256) s += sqn[r];
    double ds = 0.0;
    for (int r = t; r < NTILES; r += 256) ds += (double)partial[r];
    #pragma unroll
    for (int o = 1; o < 64; o <<= 1) { s += __shfl_xor(s, o); ds += __shfl_xor(ds, o); }
    __shared__ float redf[4];
    __shared__ double redd[4];
    if (lane == 0) { redf[wave] = s; redd[wave] = ds; }
    __syncthreads();
    if (t == 0) {
        float sumsq = redf[0] + redf[1] + redf[2] + redf[3];
        double md = (redd[0] + redd[1] + redd[2] + redd[3]) / ((double)NROWS * (double)NROWS);
        out[0] = (float)DCOLS / sumsq + (float)log(md);
    }
}

extern "C" void kernel_launch(void* const* d_in, const int* in_sizes, int n_in,
                              void* d_out, int out_size, void* d_ws, size_t ws_size,
                              hipStream_t stream) {
    const float* emb = (const float*)d_in[0];
    float* out = (float*)d_out;
    char* ws = (char*)d_ws;

    float*  inv     = (float*)ws;                    // 8192 f32
    float*  colsum  = (float*)(ws + 32768);          // 256 f32
    float*  sqn     = (float*)(ws + 36864);          // 8192 f32
    float*  partial = (float*)(ws + 69632);          // 2080 f32
    __hip_bfloat16* cbf = (__hip_bfloat16*)(ws + 131072); // 8192*256 bf16 = 4 MB

    hipMemsetAsync(colsum, 0, DCOLS * sizeof(float), stream);
    k12_fused <<<NROWS / 32, 256, 0, stream>>>(emb, inv, colsum);
    k3_center <<<NROWS / 32, 256, 0, stream>>>(emb, inv, colsum, cbf, sqn);
    k4_dist   <<<NTILES, 256, 0, stream>>>(cbf, sqn, partial);
    k5_final  <<<1, 256, 0, stream>>>(sqn, partial, out);
}

// Round 6
// 68.390 us; speedup vs baseline: 2.3130x; 1.1116x over previous
//
#include <hip/hip_runtime.h>
#include <hip/hip_bf16.h>

#define NROWS 8192
#define DCOLS 256
#define NTILES 2080   // 64*65/2 upper-triangle 128x128 tiles
constexpr float EPSV = 1e-6f;

typedef __attribute__((ext_vector_type(8))) short short8;
typedef __attribute__((ext_vector_type(4))) float f32x4;

__device__ __forceinline__ void async16(void* lds, const void* g) {
    __builtin_amdgcn_global_load_lds(
        (const __attribute__((address_space(1))) void*)g,
        (__attribute__((address_space(3))) void*)lds, 16, 0, 0);
}

// ---------------- K12: row norms + column sums, single pass ----------------
__global__ void k12_fused(const float* __restrict__ in, float* __restrict__ inv,
                          float* __restrict__ colsum) {
    int t = threadIdx.x, lane = t & 63, wave = t >> 6;
    int r0 = blockIdx.x * 32;
    __shared__ float cs[4][256];
    float4 acc4 = {0.f, 0.f, 0.f, 0.f};
    #pragma unroll
    for (int rr = 0; rr < 8; ++rr) {
        int row = r0 + wave * 8 + rr;
        float4 v = *reinterpret_cast<const float4*>(&in[row * DCOLS + lane * 4]);
        float s = v.x * v.x + v.y * v.y + v.z * v.z + v.w * v.w;
        #pragma unroll
        for (int o = 1; o < 64; o <<= 1) s += __shfl_xor(s, o);
        float iv = 1.0f / (sqrtf(s) + EPSV);
        if (lane == 0) inv[row] = iv;
        acc4.x += v.x * iv; acc4.y += v.y * iv; acc4.z += v.z * iv; acc4.w += v.w * iv;
    }
    *reinterpret_cast<float4*>(&cs[wave][lane * 4]) = acc4;
    __syncthreads();
    atomicAdd(&colsum[t], cs[0][t] + cs[1][t] + cs[2][t] + cs[3][t]);
}

// ---------------- K3: center, write bf16 c, per-row sq_norms ----------------
__global__ void k3_center(const float* __restrict__ in, const float* __restrict__ inv,
                          const float* __restrict__ colsum,
                          __hip_bfloat16* __restrict__ cbf, float* __restrict__ sqn) {
    int t = threadIdx.x, lane = t & 63, wave = t >> 6;
    int r0 = blockIdx.x * 32;
    float4 m4 = *reinterpret_cast<const float4*>(&colsum[lane * 4]);
    const float invN = 1.0f / NROWS;
    m4.x *= invN; m4.y *= invN; m4.z *= invN; m4.w *= invN;
    #pragma unroll
    for (int rr = 0; rr < 8; ++rr) {
        int row = r0 + wave * 8 + rr;
        float iv = inv[row];
        float4 v = *reinterpret_cast<const float4*>(&in[row * DCOLS + lane * 4]);
        float4 cv = {v.x * iv - m4.x, v.y * iv - m4.y, v.z * iv - m4.z, v.w * iv - m4.w};
        __hip_bfloat16 hb[4] = {__float2bfloat16(cv.x), __float2bfloat16(cv.y),
                                __float2bfloat16(cv.z), __float2bfloat16(cv.w)};
        *reinterpret_cast<ushort4*>(&cbf[row * DCOLS + lane * 4]) = *reinterpret_cast<ushort4*>(hb);
        float s = cv.x * cv.x + cv.y * cv.y + cv.z * cv.z + cv.w * cv.w;
        #pragma unroll
        for (int o = 1; o < 64; o <<= 1) s += __shfl_xor(s, o);
        if (lane == 0) sqn[row] = s;
    }
}

// ---------------- K4: 128x128 tile, 8 waves (each 64x32), dbuf BK=64 ----------------
// Wave w: wr=w>>2 (row half), wc=w&3 (col quarter). acc[4][2] 16x16 frags.
// Staging: 32 x 1KB chunks per k-slice (16 A + 16 B), 4 async16 per wave.
// Swizzle on GLOBAL source (LDS linear), XOR involution byte^=((row&7)<<4).
__global__ __launch_bounds__(512, 4) void k4_dist(const __hip_bfloat16* __restrict__ cbf,
                                                  const float* __restrict__ sqn,
                                                  float* __restrict__ partial) {
    __shared__ ushort As[2][128 * 64];   // 2 x 16KB
    __shared__ ushort Bs[2][128 * 64];
    __shared__ float red8[8];

    int bid = blockIdx.x;
    int idx = (bid & 7) * (NTILES / 8) + (bid >> 3);   // XCD swizzle, 2080%8==0
    int q = (int)((sqrtf(8.0f * (float)idx + 1.0f) - 1.0f) * 0.5f);
    while ((q + 1) * (q + 2) / 2 <= idx) ++q;
    while (q * (q + 1) / 2 > idx) --q;
    int p = idx - q * (q + 1) / 2;

    int brow = p * 128, bcol = q * 128;
    int t = threadIdx.x, lane = t & 63, wave = t >> 6;
    int wr = wave >> 2, wc = wave & 3;

    // lane l covers LDS row r0+(l>>3), 16B chunk ((l&7)^(l>>3)) of the 128B row
    int laneOff = ((lane >> 3) * 512) + ((((lane & 7) ^ (lane >> 3)) & 7) << 4);
    const char* Ab = (const char*)cbf + (size_t)brow * 512 + laneOff;
    const char* Bb = (const char*)cbf + (size_t)bcol * 512 + laneOff;
    int ra = 16 * wave;        // this wave's A/B chunk rows: ra, ra+8

    f32x4 acc[4][2] = {};

    // prologue: stage k-slice 0 into buffer 0
    async16(&As[0][ra * 64], Ab + ra * 512);
    async16(&As[0][(ra + 8) * 64], Ab + (ra + 8) * 512);
    async16(&Bs[0][ra * 64], Bb + ra * 512);
    async16(&Bs[0][(ra + 8) * 64], Bb + (ra + 8) * 512);
    __syncthreads();

    #pragma unroll
    for (int s = 0; s < 4; ++s) {
        if (s < 3) {
            int nb = (s + 1) & 1, kb = (s + 1) * 128;
            async16(&As[nb][ra * 64], Ab + ra * 512 + kb);
            async16(&As[nb][(ra + 8) * 64], Ab + (ra + 8) * 512 + kb);
            async16(&Bs[nb][ra * 64], Bb + ra * 512 + kb);
            async16(&Bs[nb][(ra + 8) * 64], Bb + (ra + 8) * 512 + kb);
        }
        int b = s & 1;
        #pragma unroll
        for (int kk = 0; kk < 2; ++kk) {
            short8 af[4], bfr[2];
            int bc = kk * 64 + ((lane >> 4) << 4);
            #pragma unroll
            for (int m = 0; m < 4; ++m) {
                int row = wr * 64 + m * 16 + (lane & 15);
                int off = (row * 128 + bc) ^ ((row & 7) << 4);
                af[m] = *reinterpret_cast<const short8*>(reinterpret_cast<const char*>(As[b]) + off);
            }
            #pragma unroll
            for (int n = 0; n < 2; ++n) {
                int row = wc * 32 + n * 16 + (lane & 15);
                int off = (row * 128 + bc) ^ ((row & 7) << 4);
                bfr[n] = *reinterpret_cast<const short8*>(reinterpret_cast<const char*>(Bs[b]) + off);
            }
            #pragma unroll
            for (int m = 0; m < 4; ++m)
                #pragma unroll
                for (int n = 0; n < 2; ++n)
                    acc[m][n] = __builtin_amdgcn_mfma_f32_16x16x32_bf16(af[m], bfr[n], acc[m][n], 0, 0, 0);
        }
        __syncthreads();
    }

    // epilogue: sq_dist = sqn_i + sqn_j - 2*gram; accumulate sqrt
    float local = 0.0f;
    int r4 = (lane >> 4) * 4;
    int cn = lane & 15;
    #pragma unroll
    for (int n = 0; n < 2; ++n) {
        int j = bcol + wc * 32 + n * 16 + cn;
        float sj = sqn[j];
        #pragma unroll
        for (int m = 0; m < 4; ++m) {
            int i0 = brow + wr * 64 + m * 16 + r4;
            #pragma unroll
            for (int r = 0; r < 4; ++r) {
                float sq = sqn[i0 + r] + sj - 2.0f * acc[m][n][r];
                local += (sq > 0.0f) ? sqrtf(sq) : 0.0f;
            }
        }
    }
    #pragma unroll
    for (int o = 1; o < 64; o <<= 1) local += __shfl_xor(local, o);
    if (lane == 0) red8[wave] = local;
    __syncthreads();
    if (t == 0) {
        float w = (p == q) ? 1.0f : 2.0f;
        float s8 = 0.f;
        #pragma unroll
        for (int i = 0; i < 8; ++i) s8 += red8[i];
        partial[idx] = w * s8;
    }
}

// ---------------- K5: final scalar ----------------
__global__ void k5_final(const float* __restrict__ sqn, const float* __restrict__ partial,
                         float* __restrict__ out) {
    int t = threadIdx.x;
    int lane = t & 63, wave = t >> 6;
    float s = 0.0f;
    for (int r = t; r < NROWS; r += 1024) s += sqn[r];
    double ds = 0.0;
    for (int r = t; r < NTILES; r += 1024) ds += (double)partial[r];
    #pragma unroll
    for (int o = 1; o < 64; o <<= 1) { s += __shfl_xor(s, o); ds += __shfl_xor(ds, o); }
    __shared__ float redf[16];
    __shared__ double redd[16];
    if (lane == 0) { redf[wave] = s; redd[wave] = ds; }
    __syncthreads();
    if (t == 0) {
        float sumsq = 0.f; double sd = 0.0;
        #pragma unroll
        for (int i = 0; i < 16; ++i) { sumsq += redf[i]; sd += redd[i]; }
        double md = sd / ((double)NROWS * (double)NROWS);
        out[0] = (float)DCOLS / sumsq + (float)log(md);
    }
}

extern "C" void kernel_launch(void* const* d_in, const int* in_sizes, int n_in,
                              void* d_out, int out_size, void* d_ws, size_t ws_size,
                              hipStream_t stream) {
    const float* emb = (const float*)d_in[0];
    float* out = (float*)d_out;
    char* ws = (char*)d_ws;

    float*  inv     = (float*)ws;                    // 8192 f32
    float*  colsum  = (float*)(ws + 32768);          // 256 f32
    float*  sqn     = (float*)(ws + 36864);          // 8192 f32
    float*  partial = (float*)(ws + 69632);          // 2080 f32
    __hip_bfloat16* cbf = (__hip_bfloat16*)(ws + 131072); // 8192*256 bf16 = 4 MB

    (void)hipMemsetAsync(colsum, 0, DCOLS * sizeof(float), stream);
    k12_fused <<<NROWS / 32, 256, 0, stream>>>(emb, inv, colsum);
    k3_center <<<NROWS / 32, 256, 0, stream>>>(emb, inv, colsum, cbf, sqn);
    k4_dist   <<<NTILES, 512, 0, stream>>>(cbf, sqn, partial);
    k5_final  <<<1, 1024, 0, stream>>>(sqn, partial, out);
}